// Round 2
// baseline (681.297 us; speedup 1.0000x reference)
//
#include <hip/hip_runtime.h>

// MDTA attention, B=8 C=192 H=W=128 heads=4 (ch=48), all-bf16 MFMA pipeline.
// R3: gemm_kernel restructured to 2-phase double-buffered pipeline (T3-minimum):
//     stage(t+1) into back LDS buffer BEFORE compute(t), single barrier per
//     K-step. 80KB LDS (2 blocks/CU). Hides global_load_lds latency under MFMA.

#define HW 16384

using f32x4  = __attribute__((ext_vector_type(4))) float;
using bf16x8 = __attribute__((ext_vector_type(8))) __bf16;
using u16x8  = __attribute__((ext_vector_type(8))) unsigned short;
typedef unsigned short u16;

__device__ __forceinline__ u16 f2bf(float f) {
  unsigned u = __builtin_bit_cast(unsigned, f);
  u = (u + 0x7fffu + ((u >> 16) & 1u)) >> 16;   // RNE
  return (u16)u;
}
__device__ __forceinline__ float bf2f(u16 s) {
  unsigned u = ((unsigned)s) << 16;
  return __builtin_bit_cast(float, u);
}

// async global->LDS, 16B/lane; LDS dest is wave-uniform base + lane*16
__device__ __forceinline__ void g2l16(const void* g, void* l) {
  __builtin_amdgcn_global_load_lds(
      (const __attribute__((address_space(1))) unsigned int*)g,
      (__attribute__((address_space(3))) unsigned int*)l, 16, 0, 0);
}

// ---------------- W1 pack: kv_w [384][192] fp32 -> bf16 ----------------
__global__ __launch_bounds__(256) void pack_w1(
    const float* __restrict__ kv_w, u16* __restrict__ W1) {
  int i = blockIdx.x * 256 + threadIdx.x;
  W1[i] = f2bf(kv_w[i]);
}

// ---------------- W4[o][seg*192+c] = sum_ic q_dw_w[(o*192+ic)*9+seg]*q_w[ic*192+c]
__global__ __launch_bounds__(192) void make_w4(
    const float* __restrict__ q_w, const float* __restrict__ q_dw_w,
    u16* __restrict__ W4) {
  const int o = blockIdx.x / 9, seg = blockIdx.x % 9;
  const int c = threadIdx.x;
  float s = 0.f;
  for (int ic = 0; ic < 192; ++ic)
    s += q_dw_w[(o * 192 + ic) * 9 + seg] * q_w[ic * 192 + c];
  W4[o * 1728 + seg * 192 + c] = f2bf(s);
}

// ---------------- transpose [b][C][HW] -> [b][HW][192] bf16 ----------------
template <typename TIn>
__global__ __launch_bounds__(256) void transpose_kernel(
    const TIn* __restrict__ src, u16* __restrict__ dst, int srcCstride) {
  __shared__ u16 tile[32][34];
  const int bz = blockIdx.z;
  const int n0 = blockIdx.x * 32;
  const int c0 = blockIdx.y * 32;
  const TIn* s = src + (long)bz * srcCstride * HW;
  u16* d = dst + (long)bz * HW * 192;
  const int tx = threadIdx.x & 31;
  const int ty = threadIdx.x >> 5;
#pragma unroll
  for (int i = 0; i < 32; i += 8) {
    if constexpr (sizeof(TIn) == 4)
      tile[ty + i][tx] = f2bf(((const float*)s)[(long)(c0 + ty + i) * HW + n0 + tx]);
    else
      tile[ty + i][tx] = ((const u16*)s)[(long)(c0 + ty + i) * HW + n0 + tx];
  }
  __syncthreads();
#pragma unroll
  for (int i = 0; i < 32; i += 8)
    d[(long)(n0 + ty + i) * 192 + c0 + tx] = tile[tx][ty + i];
}

// ---------------- main MFMA GEMM, BK=64, 2-phase double-buffered ----------------
// C[b][m][n] = sum_k A[m][k] * Bt[b][n][k], K = NSEG*192.
// NSEG==9: segment s=(dy,dx) reads Bt row (n + dy*128 + dx), zero page at borders.
// Tile 64x256x64; 4 waves 2x2, each 32x128. LDS slot = staging lane index, so
// frag read addr = base + lane*16 (conflict-free) and staging is the identity.
// Pipeline: stage(t+1)->back buffer, ds_read+MFMA from front, ONE barrier/K-step.
template <int NSEG, bool OUT_BF16, bool FUSE_RQ>
__global__ __launch_bounds__(256, 2) void gemm_kernel(
    const u16* __restrict__ A, const u16* __restrict__ Bt,
    void* __restrict__ Cout, const u16* __restrict__ zp,
    int M, long aBatchStride, float* __restrict__ rqs) {
  __shared__ __align__(16) u16 shA[2][4096];    // 2 x (64 rows x 64 k)
  __shared__ __align__(16) u16 shB[2][16384];   // 2 x (256 rows x 64 k)
  const int Ktot = NSEG * 192;
  const int NT = NSEG * 3;                      // BK=64 steps
  const int tid = threadIdx.x;
  const int w = tid >> 6;
  const int lane = tid & 63;
  const int rl = lane & 15;
  const int q4 = lane >> 4;
  const int wm = w & 1, wn = w >> 1;
  const int b = blockIdx.z;
  const int n0 = blockIdx.x * 256;
  const int m0 = blockIdx.y * 64;

  const u16* Ab = A + (long)b * aBatchStride + (long)m0 * Ktot;
  const u16* Btb = Bt + (long)b * HW * 192;
  const char* asrc = (const char*)(Ab + (long)(w * 16 + rl) * Ktot) + q4 * 16;
  const char* zpp = (const char*)zp + q4 * 16;

  // per-j base pointers into Bt (seg-0 row) + coords for border check
  const char* p0[4];
  int xx[4], yy[4];
#pragma unroll
  for (int j = 0; j < 4; ++j) {
    int n = n0 + (w * 4 + j) * 16 + rl;
    p0[j] = (const char*)(Btb + (long)n * 192) + q4 * 16;
    xx[j] = n & 127;
    yy[j] = n >> 7;
  }

  f32x4 acc[2][8];
#pragma unroll
  for (int i = 0; i < 2; ++i)
#pragma unroll
    for (int j = 0; j < 8; ++j) acc[i][j] = f32x4{0.f, 0.f, 0.f, 0.f};

  const int lane_off = lane * 8;   // u16 offset of this lane's frag slot

  // issue all global_load_lds for K-step t into buffer sbuf
  auto stage = [&](int t, int sbuf) {
    const long ao = (long)t * 128;               // A byte offset = t*64 u16 *2
    g2l16(asrc + ao, &shA[sbuf][w * 1024]);
    g2l16(asrc + ao + 64, &shA[sbuf][w * 1024 + 512]);
    const char* bp[4];
    int kb;
    if constexpr (NSEG == 1) {
      kb = t * 128;
#pragma unroll
      for (int j = 0; j < 4; ++j) bp[j] = p0[j];
    } else {
      const int seg = t / 3;
      kb = (t - seg * 3) * 128;
      const int dy = seg / 3 - 1, dx = seg % 3 - 1;
      const int roff = (dy * 128 + dx) * 384;    // byte offset between Bt rows
#pragma unroll
      for (int j = 0; j < 4; ++j) {
        bool ok = ((unsigned)(xx[j] + dx) < 128u) && ((unsigned)(yy[j] + dy) < 128u);
        bp[j] = ok ? p0[j] + roff : zpp;
      }
    }
#pragma unroll
    for (int j = 0; j < 4; ++j) {
      g2l16(bp[j] + kb, &shB[sbuf][(w * 4 + j) * 1024]);
      g2l16(bp[j] + kb + 64, &shB[sbuf][(w * 4 + j) * 1024 + 512]);
    }
  };

  // ds_read fragments from buffer cbuf and run the 32-MFMA cluster
  auto compute = [&](int cbuf) {
    bf16x8 af[2][2];
#pragma unroll
    for (int i = 0; i < 2; ++i)
#pragma unroll
      for (int h = 0; h < 2; ++h)
        af[i][h] = *(const bf16x8*)&shA[cbuf][(wm * 2 + i) * 1024 + h * 512 + lane_off];
#pragma unroll
    for (int jh = 0; jh < 2; ++jh) {
      bf16x8 bfr[4][2];
#pragma unroll
      for (int j2 = 0; j2 < 4; ++j2)
#pragma unroll
        for (int h = 0; h < 2; ++h)
          bfr[j2][h] = *(const bf16x8*)&shB[cbuf][(wn * 8 + jh * 4 + j2) * 1024 + h * 512 + lane_off];
#pragma unroll
      for (int i = 0; i < 2; ++i)
#pragma unroll
        for (int j2 = 0; j2 < 4; ++j2) {
          const int j = jh * 4 + j2;
          acc[i][j] = __builtin_amdgcn_mfma_f32_16x16x32_bf16(af[i][0], bfr[j2][0], acc[i][j], 0, 0, 0);
          acc[i][j] = __builtin_amdgcn_mfma_f32_16x16x32_bf16(af[i][1], bfr[j2][1], acc[i][j], 0, 0, 0);
        }
    }
  };

  // prologue
  stage(0, 0);
  __syncthreads();                 // vmcnt(0) drain + barrier: buf0 ready
  int cur = 0;
  for (int t = 0; t < NT - 1; ++t) {
    stage(t + 1, cur ^ 1);         // issue next-tile loads (latency hides under MFMA)
    compute(cur);
    __syncthreads();               // drains stage(t+1) loads; back buffer ready
    cur ^= 1;
  }
  compute(cur);                    // epilogue tile: no prefetch, no barrier needed

  // epilogue: D row m = quad*4+reg, col n = lane&15  [m89/m91 mapping]
  const int mb = m0 + wm * 32;
  const int nb = n0 + wn * 128;
  if constexpr (OUT_BF16) {
    u16* Cb = (u16*)Cout + (long)b * M * HW;
#pragma unroll
    for (int i = 0; i < 2; ++i)
#pragma unroll
      for (int j = 0; j < 8; ++j)
#pragma unroll
        for (int r = 0; r < 4; ++r)
          Cb[(long)(mb + i * 16 + q4 * 4 + r) * HW + nb + j * 16 + rl] = f2bf(acc[i][j][r]);
  } else {
    float* Cb = (float*)Cout + (long)b * M * HW;
#pragma unroll
    for (int i = 0; i < 2; ++i)
#pragma unroll
      for (int j = 0; j < 8; ++j)
#pragma unroll
        for (int r = 0; r < 4; ++r)
          Cb[(long)(mb + i * 16 + q4 * 4 + r) * HW + nb + j * 16 + rl] = acc[i][j][r];
  }
  if constexpr (FUSE_RQ) {
    // per-row sum of squares over this block's 256-col slice -> atomicAdd
#pragma unroll
    for (int i = 0; i < 2; ++i)
#pragma unroll
      for (int r = 0; r < 4; ++r) {
        float s = 0.f;
#pragma unroll
        for (int j = 0; j < 8; ++j) s += acc[i][j][r] * acc[i][j][r];
        s += __shfl_xor(s, 1, 64);
        s += __shfl_xor(s, 2, 64);
        s += __shfl_xor(s, 4, 64);
        s += __shfl_xor(s, 8, 64);
        if (rl == 0)
          atomicAdd(&rqs[b * 192 + mb + i * 16 + q4 * 4 + r], s);
      }
  }
}

// ---------------- depthwise 3x3, pad 1 (optional fused sumsq) ----------------
template <bool FUSE_NORM>
__global__ __launch_bounds__(256) void dwconv_kernel(
    const u16* __restrict__ kv, const float* __restrict__ dww,
    u16* __restrict__ dst, int cbase, int dstCstride, float* __restrict__ rks) {
  __shared__ __align__(16) u16 sp[HW];
  const int c = blockIdx.x;       // 0..191
  const int b = blockIdx.y;       // 0..7
  const int c2 = cbase + c;       // channel in kv (0..383)
  const u16* src = kv + ((long)b * 384 + c2) * HW;
  u16* out = dst + ((long)b * dstCstride + c) * HW;
  const int tid = threadIdx.x;
#pragma unroll
  for (int it = 0; it < 8; ++it)
    ((u16x8*)sp)[it * 256 + tid] = ((const u16x8*)src)[it * 256 + tid];
  __syncthreads();
  float w9[9];
#pragma unroll
  for (int t = 0; t < 9; ++t) w9[t] = dww[c2 * 9 + t];
  float ssum = 0.f;
  for (int o = 0; o < 8; ++o) {
    const int base = o * 2048 + tid * 8;
    const int yy = base >> 7;
    const int x0 = base & 127;
    float vv[3][10];
#pragma unroll
    for (int r = 0; r < 3; ++r) {
      int yr = yy + r - 1;
      if (yr >= 0 && yr < 128) {
        const u16* rp = sp + yr * 128 + x0;
        u16x8 mid = *(const u16x8*)rp;
#pragma unroll
        for (int i2 = 0; i2 < 8; ++i2) vv[r][1 + i2] = bf2f(mid[i2]);
        vv[r][0] = (x0 > 0)   ? bf2f(rp[-1]) : 0.f;
        vv[r][9] = (x0 < 120) ? bf2f(rp[8])  : 0.f;
      } else {
#pragma unroll
        for (int i2 = 0; i2 < 10; ++i2) vv[r][i2] = 0.f;
      }
    }
    u16x8 ov;
#pragma unroll
    for (int i2 = 0; i2 < 8; ++i2) {
      float s = 0.f;
#pragma unroll
      for (int r = 0; r < 3; ++r)
#pragma unroll
        for (int d = 0; d < 3; ++d) s += w9[r * 3 + d] * vv[r][i2 + d];
      if constexpr (FUSE_NORM) ssum += s * s;
      ov[i2] = f2bf(s);
    }
    *(u16x8*)(out + base) = ov;
  }
  if constexpr (FUSE_NORM) {
#pragma unroll
    for (int off = 32; off; off >>= 1) ssum += __shfl_down(ssum, off, 64);
    if ((tid & 63) == 0) atomicAdd(&rks[b * 192 + c], ssum);
  }
}

// ---------------- Gram, split-K: 32 (b,h) x 8 k-chunks, atomicAdd ----------------
__global__ __launch_bounds__(256) void gram_kernel(
    const u16* __restrict__ qq, const u16* __restrict__ kk, float* __restrict__ gram) {
  __shared__ float red[4 * 2304];
  const int bh = blockIdx.x;             // 0..31
  const int kc = blockIdx.y;             // 0..7
  const int b = bh >> 2, h = bh & 3;
  const u16* qb = qq + ((long)b * 192 + h * 48) * HW;
  const u16* kb = kk + ((long)b * 192 + h * 48) * HW;
  const int tid = threadIdx.x, w = tid >> 6, lane = tid & 63;
  const int rl = lane & 15, q4 = lane >> 4;
  f32x4 acc[3][3];
#pragma unroll
  for (int i = 0; i < 3; ++i)
#pragma unroll
    for (int j = 0; j < 3; ++j) acc[i][j] = f32x4{0.f, 0.f, 0.f, 0.f};
  for (int tt = 0; tt < 16; ++tt) {
    const int k0 = ((kc * 16 + tt) * 4 + w) * 32 + q4 * 8;
    bf16x8 af[3], bfr[3];
#pragma unroll
    for (int i = 0; i < 3; ++i) af[i] = *(const bf16x8*)(qb + (long)(i * 16 + rl) * HW + k0);
#pragma unroll
    for (int j = 0; j < 3; ++j) bfr[j] = *(const bf16x8*)(kb + (long)(j * 16 + rl) * HW + k0);
#pragma unroll
    for (int i = 0; i < 3; ++i)
#pragma unroll
      for (int j = 0; j < 3; ++j)
        acc[i][j] = __builtin_amdgcn_mfma_f32_16x16x32_bf16(af[i], bfr[j], acc[i][j], 0, 0, 0);
  }
#pragma unroll
  for (int i = 0; i < 3; ++i)
#pragma unroll
    for (int j = 0; j < 3; ++j)
#pragma unroll
      for (int r = 0; r < 4; ++r)
        red[w * 2304 + (i * 16 + q4 * 4 + r) * 48 + j * 16 + rl] = acc[i][j][r];
  __syncthreads();
  for (int e = tid; e < 2304; e += 256)
    atomicAdd(&gram[(long)bh * 2304 + e], red[e] + red[2304 + e] + red[4608 + e] + red[6912 + e]);
}

// ---------------- softmax over dl (one wave per (b,h,cl) row) ----------------
__global__ __launch_bounds__(64) void softmax_kernel(
    const float* __restrict__ gram, const float* __restrict__ rqs,
    const float* __restrict__ rks, const float* __restrict__ temperature,
    float* __restrict__ attn) {
  const int R = blockIdx.x;            // b*192 + h*48 + cl
  const int lane = threadIdx.x;
  const int b = R / 192;
  const int h = (R % 192) / 48;
  const float ts = temperature[h] * 3.8712010109078907f;  // ln(48)
  const float rq = rsqrtf(fmaxf(rqs[R], 1e-24f));
  float val = -3.0e38f;
  if (lane < 48) {
    const float rk = rsqrtf(fmaxf(rks[b * 192 + h * 48 + lane], 1e-24f));
    val = gram[(long)R * 48 + lane] * rq * rk * ts;
  }
  float mx = val;
#pragma unroll
  for (int off = 32; off; off >>= 1) mx = fmaxf(mx, __shfl_xor(mx, off, 64));
  float ex = (lane < 48) ? expf(val - mx) : 0.f;
  float sm = ex;
#pragma unroll
  for (int off = 32; off; off >>= 1) sm += __shfl_xor(sm, off, 64);
  if (lane < 48) attn[(long)R * 48 + lane] = ex / sm;
}

// ---------------- PA[b][o][dg] = sum_cl proj[o][hg*48+cl] * attn[b,hg,cl,dl] ----
__global__ __launch_bounds__(192) void pa_kernel(
    const float* __restrict__ proj_w, const float* __restrict__ attn,
    u16* __restrict__ PA) {
  const int b = blockIdx.x;     // 0..7
  const int o = blockIdx.y;     // 0..191
  const int dg = threadIdx.x;   // 0..191
  const int hg = dg / 48, dl = dg % 48;
  const float* arow = attn + ((long)(b * 4 + hg) * 48) * 48 + dl;
  const float* prow = proj_w + o * 192 + hg * 48;
  float s = 0.f;
#pragma unroll
  for (int cl = 0; cl < 48; ++cl) s += prow[cl] * arow[(long)cl * 48];
  PA[((long)b * 192 + o) * 192 + dg] = f2bf(s);
}

// ---------------- launch ----------------
extern "C" void kernel_launch(void* const* d_in, const int* in_sizes, int n_in,
                              void* d_out, int out_size, void* d_ws, size_t ws_size,
                              hipStream_t stream) {
  (void)in_sizes; (void)n_in; (void)out_size; (void)ws_size;
  const float* x        = (const float*)d_in[0];
  const float* y        = (const float*)d_in[1];
  const float* kv_w     = (const float*)d_in[2];
  const float* kv_dw_w  = (const float*)d_in[3];
  const float* q_w      = (const float*)d_in[4];
  const float* q_dw_w   = (const float*)d_in[5];
  const float* proj_w   = (const float*)d_in[6];
  const float* temperature = (const float*)d_in[7];

  char* ws = (char*)d_ws;
  u16* KV = (u16*)(ws + 0L);           // kv[8][384][HW]; later v into ch 0..191
  u16* R0 = (u16*)(ws + 100663296L);   // k [8][192][HW]
  u16* R1 = (u16*)(ws + 150994944L);   // q [8][192][HW]
  u16* R2 = (u16*)(ws + 201326592L);   // yT -> xT -> vT [8][HW][192]
  char* tail = ws + 251658240L;
  u16*   zp   = (u16*)(tail + 0);        // 512 B zeros
  float* rqs  = (float*)(tail + 512);    // 6144 B
  float* rks  = (float*)(tail + 6656);   // 6144 B
  float* gram = (float*)(tail + 12800);  // 294912 B
  float* attn = (float*)(tail + 307712); // 294912 B
  u16*   W1   = (u16*)(tail + 602624);   // 147456 B
  u16*   W4   = (u16*)(tail + 750080);   // 663552 B
  u16*   PA   = (u16*)(tail + 1413632);  // 589824 B

  hipMemsetAsync(tail, 0, 307712, stream);   // zp + rqs + rks + gram
  pack_w1<<<288, 256, 0, stream>>>(kv_w, W1);
  make_w4<<<1728, 192, 0, stream>>>(q_w, q_dw_w, W4);

  // ---- q path: yT -> q (3x3 merged) with fused rq ----
  transpose_kernel<float><<<dim3(512, 6, 8), 256, 0, stream>>>(y, R2, 192);
  gemm_kernel<9, true, true><<<dim3(64, 3, 8), 256, 0, stream>>>(W4, R2, R1, zp, 192, 0, rqs);

  // ---- kv path ----
  transpose_kernel<float><<<dim3(512, 6, 8), 256, 0, stream>>>(x, R2, 192);
  gemm_kernel<1, true, false><<<dim3(64, 6, 8), 256, 0, stream>>>(W1, R2, KV, zp, 384, 0, nullptr);
  dwconv_kernel<true><<<dim3(192, 8), 256, 0, stream>>>(KV, kv_dw_w, R0, 0, 192, rks);
  dwconv_kernel<false><<<dim3(192, 8), 256, 0, stream>>>(KV, kv_dw_w, KV, 192, 384, nullptr);
  transpose_kernel<u16><<<dim3(512, 6, 8), 256, 0, stream>>>(KV, R2, 384);

  // ---- attention + projection ----
  gram_kernel<<<dim3(32, 8), 256, 0, stream>>>(R1, R0, gram);
  softmax_kernel<<<1536, 64, 0, stream>>>(gram, rqs, rks, temperature, attn);
  pa_kernel<<<dim3(8, 192), 192, 0, stream>>>(proj_w, attn, PA);
  gemm_kernel<1, false, false><<<dim3(64, 3, 8), 256, 0, stream>>>(PA, R2, d_out, zp, 192, 36864, nullptr);
}

// Round 3
// 643.095 us; speedup vs baseline: 1.0594x; 1.0594x over previous
//
#include <hip/hip_runtime.h>

// MDTA attention, B=8 C=192 H=W=128 heads=4 (ch=48), all-bf16 MFMA pipeline.
// R4: gemm rewritten: BM=192 (all of M) x BN=256, 8 waves (2x4), 512 threads,
//     double-buffered 112KB LDS, counted s_waitcnt vmcnt(7) pipeline with
//     prefetch distance 2 (T3+T4): stage tile t at iter t-2, never drain to 0
//     in the main loop. Raw s_barrier; lgkmcnt(0)+sched_barrier before reuse.

#define HW 16384

using f32x4  = __attribute__((ext_vector_type(4))) float;
using bf16x8 = __attribute__((ext_vector_type(8))) __bf16;
using u16x8  = __attribute__((ext_vector_type(8))) unsigned short;
typedef unsigned short u16;

__device__ __forceinline__ u16 f2bf(float f) {
  unsigned u = __builtin_bit_cast(unsigned, f);
  u = (u + 0x7fffu + ((u >> 16) & 1u)) >> 16;   // RNE
  return (u16)u;
}
__device__ __forceinline__ float bf2f(u16 s) {
  unsigned u = ((unsigned)s) << 16;
  return __builtin_bit_cast(float, u);
}

// async global->LDS, 16B/lane; LDS dest is wave-uniform base + lane*16
__device__ __forceinline__ void g2l16(const void* g, void* l) {
  __builtin_amdgcn_global_load_lds(
      (const __attribute__((address_space(1))) unsigned int*)g,
      (__attribute__((address_space(3))) unsigned int*)l, 16, 0, 0);
}

// ---------------- W1 pack: kv_w [384][192] fp32 -> bf16 ----------------
__global__ __launch_bounds__(256) void pack_w1(
    const float* __restrict__ kv_w, u16* __restrict__ W1) {
  int i = blockIdx.x * 256 + threadIdx.x;
  W1[i] = f2bf(kv_w[i]);
}

// ---------------- W4[o][seg*192+c] = sum_ic q_dw_w[(o*192+ic)*9+seg]*q_w[ic*192+c]
__global__ __launch_bounds__(192) void make_w4(
    const float* __restrict__ q_w, const float* __restrict__ q_dw_w,
    u16* __restrict__ W4) {
  const int o = blockIdx.x / 9, seg = blockIdx.x % 9;
  const int c = threadIdx.x;
  float s = 0.f;
  for (int ic = 0; ic < 192; ++ic)
    s += q_dw_w[(o * 192 + ic) * 9 + seg] * q_w[ic * 192 + c];
  W4[o * 1728 + seg * 192 + c] = f2bf(s);
}

// ---------------- transpose [b][C][HW] -> [b][HW][192] bf16 ----------------
template <typename TIn>
__global__ __launch_bounds__(256) void transpose_kernel(
    const TIn* __restrict__ src, u16* __restrict__ dst, int srcCstride) {
  __shared__ u16 tile[32][34];
  const int bz = blockIdx.z;
  const int n0 = blockIdx.x * 32;
  const int c0 = blockIdx.y * 32;
  const TIn* s = src + (long)bz * srcCstride * HW;
  u16* d = dst + (long)bz * HW * 192;
  const int tx = threadIdx.x & 31;
  const int ty = threadIdx.x >> 5;
#pragma unroll
  for (int i = 0; i < 32; i += 8) {
    if constexpr (sizeof(TIn) == 4)
      tile[ty + i][tx] = f2bf(((const float*)s)[(long)(c0 + ty + i) * HW + n0 + tx]);
    else
      tile[ty + i][tx] = ((const u16*)s)[(long)(c0 + ty + i) * HW + n0 + tx];
  }
  __syncthreads();
#pragma unroll
  for (int i = 0; i < 32; i += 8)
    d[(long)(n0 + ty + i) * 192 + c0 + tx] = tile[tx][ty + i];
}

// ---------------- main MFMA GEMM ----------------
// C[b][m][n] = sum_k A[m][k] * Bt[b][n][k], K = NSEG*192, BK=64.
// NSEG==9: segment s=(dy,dx) reads Bt row (n + dy*128 + dx), zero page at borders.
// Tile 192x256x64; 8 waves 2x4, each 96x64. LDS slot = staging lane index, so
// frag read addr = base + lane*16 (conflict-free) and staging is the identity.
// Slots: A (s,h) -> (s*2+h)*512 u16, s=0..11 m-subtile, h=k-half. B same, s=0..15.
// Staging per wave: 3 A slots (own subtile w, both halves + 1 of subtiles 8..11)
// and 4 B slots (subtiles 2w, 2w+1) = 7 global_load_lds -> vmcnt(7) = one tile.
template <int NSEG, bool OUT_BF16, bool FUSE_RQ>
__global__ __launch_bounds__(512, 2) void gemm_kernel(
    const u16* __restrict__ A, const u16* __restrict__ Bt,
    void* __restrict__ Cout, const u16* __restrict__ zp,
    int M, long aBatchStride, float* __restrict__ rqs) {
  __shared__ __align__(16) u16 shA[2][12288];   // 2 x (12 subtiles x 2 halves x 1KB)
  __shared__ __align__(16) u16 shB[2][16384];   // 2 x (16 subtiles x 2 halves x 1KB)
  const int Ktot = NSEG * 192;
  const int NT = NSEG * 3;                      // BK=64 steps
  const int tid = threadIdx.x;
  const int w = tid >> 6;                       // 0..7
  const int lane = tid & 63;
  const int rl = lane & 15;
  const int q4 = lane >> 4;
  const int wm = w >> 2, wn = w & 3;            // 2x4 wave grid
  const int b = blockIdx.z;
  const int n0 = blockIdx.x * 256;
  const int m0 = blockIdx.y * 192;

  const u16* Ab = A + (long)b * aBatchStride + (long)m0 * Ktot;
  const u16* Btb = Bt + (long)b * HW * 192;
  const char* zpp = (const char*)zp + q4 * 16;

  // A staging sources (per wave: subtile w halves 0,1; subtile 8+(w>>1) half w&1)
  const char* aptr0 = (const char*)(Ab + (long)(w * 16 + rl) * Ktot) + q4 * 16;
  const char* aptr1 = (const char*)(Ab + (long)((8 + (w >> 1)) * 16 + rl) * Ktot)
                      + q4 * 16 + (w & 1) * 64;

  // B staging sources: n-subtiles 2w, 2w+1
  const char* p0b[2];
  int xx[2], yy[2];
#pragma unroll
  for (int jj = 0; jj < 2; ++jj) {
    int n = n0 + (2 * w + jj) * 16 + rl;
    p0b[jj] = (const char*)(Btb + (long)n * 192) + q4 * 16;
    xx[jj] = n & 127;
    yy[jj] = n >> 7;
  }

  f32x4 acc[6][4];
#pragma unroll
  for (int i = 0; i < 6; ++i)
#pragma unroll
    for (int j = 0; j < 4; ++j) acc[i][j] = f32x4{0.f, 0.f, 0.f, 0.f};

  const int lane_off = lane * 8;   // u16 offset of this lane's frag slot

  // issue the 7 global_load_lds for K-step tt into buffer sbuf
  auto stage = [&](int tt, int sbuf) {
    u16* dA = &shA[sbuf][0];
    u16* dB = &shB[sbuf][0];
    const long ao = (long)tt * 128;              // A k byte offset
    g2l16(aptr0 + ao,      dA + (w * 2 + 0) * 512);
    g2l16(aptr0 + ao + 64, dA + (w * 2 + 1) * 512);
    g2l16(aptr1 + ao,      dA + ((8 + (w >> 1)) * 2 + (w & 1)) * 512);
    if constexpr (NSEG == 1) {
      const long kb = (long)tt * 128;
#pragma unroll
      for (int jj = 0; jj < 2; ++jj) {
        g2l16(p0b[jj] + kb,      dB + ((2 * w + jj) * 2 + 0) * 512);
        g2l16(p0b[jj] + kb + 64, dB + ((2 * w + jj) * 2 + 1) * 512);
      }
    } else {
      const int seg = tt / 3;
      const long kb = (long)(tt - seg * 3) * 128;
      const int dy = seg / 3 - 1, dx = seg % 3 - 1;
      const long roff = (long)(dy * 128 + dx) * 384;   // byte offset between Bt rows
#pragma unroll
      for (int jj = 0; jj < 2; ++jj) {
        bool ok = ((unsigned)(xx[jj] + dx) < 128u) && ((unsigned)(yy[jj] + dy) < 128u);
        const char* bp = ok ? p0b[jj] + roff : zpp;
        g2l16(bp + kb,      dB + ((2 * w + jj) * 2 + 0) * 512);
        g2l16(bp + kb + 64, dB + ((2 * w + jj) * 2 + 1) * 512);
      }
    }
  };

  // ds_read fragments from buffer cbuf and run the 48-MFMA cluster
  auto compute = [&](int cbuf) {
    const u16* sA = &shA[cbuf][0];
    const u16* sB = &shB[cbuf][0];
    bf16x8 af[6][2];
#pragma unroll
    for (int i = 0; i < 6; ++i)
#pragma unroll
      for (int h = 0; h < 2; ++h)
        af[i][h] = *(const bf16x8*)&sA[((wm * 6 + i) * 2 + h) * 512 + lane_off];
    bf16x8 bfr[4][2];
#pragma unroll
    for (int j = 0; j < 4; ++j)
#pragma unroll
      for (int h = 0; h < 2; ++h)
        bfr[j][h] = *(const bf16x8*)&sB[((wn * 4 + j) * 2 + h) * 512 + lane_off];
#pragma unroll
    for (int i = 0; i < 6; ++i)
#pragma unroll
      for (int j = 0; j < 4; ++j) {
        acc[i][j] = __builtin_amdgcn_mfma_f32_16x16x32_bf16(af[i][0], bfr[j][0], acc[i][j], 0, 0, 0);
        acc[i][j] = __builtin_amdgcn_mfma_f32_16x16x32_bf16(af[i][1], bfr[j][1], acc[i][j], 0, 0, 0);
      }
  };

  // prologue: 2 tiles in flight (14 outstanding loads/wave)
  stage(0, 0);
  stage(1, 1);
  for (int t = 0; t < NT; ++t) {
    const int cur = t & 1;
    if (t < NT - 1)
      asm volatile("s_waitcnt vmcnt(7)" ::: "memory");   // tile t landed; t+1 in flight
    else
      asm volatile("s_waitcnt vmcnt(0)" ::: "memory");   // last tile
    __builtin_amdgcn_s_barrier();                        // all waves see tile t
    compute(cur);
    asm volatile("s_waitcnt lgkmcnt(0)" ::: "memory");   // all my ds_reads done
    __builtin_amdgcn_sched_barrier(0);
    __builtin_amdgcn_s_barrier();                        // everyone done reading buf
    if (t + 2 < NT) stage(t + 2, cur);                   // overwrite safely
  }

  // epilogue: D row m = quad*4+reg, col n = lane&15  [m89/m91 mapping]
  const int mb = m0 + wm * 96;
  const int nb = n0 + wn * 64;
  if constexpr (OUT_BF16) {
    u16* Cb = (u16*)Cout + (long)b * M * HW;
#pragma unroll
    for (int i = 0; i < 6; ++i)
#pragma unroll
      for (int j = 0; j < 4; ++j)
#pragma unroll
        for (int r = 0; r < 4; ++r)
          Cb[(long)(mb + i * 16 + q4 * 4 + r) * HW + nb + j * 16 + rl] = f2bf(acc[i][j][r]);
  } else {
    float* Cb = (float*)Cout + (long)b * M * HW;
#pragma unroll
    for (int i = 0; i < 6; ++i)
#pragma unroll
      for (int j = 0; j < 4; ++j)
#pragma unroll
        for (int r = 0; r < 4; ++r)
          Cb[(long)(mb + i * 16 + q4 * 4 + r) * HW + nb + j * 16 + rl] = acc[i][j][r];
  }
  if constexpr (FUSE_RQ) {
    // per-row sum of squares over this block's 256-col slice -> atomicAdd
#pragma unroll
    for (int i = 0; i < 6; ++i)
#pragma unroll
      for (int r = 0; r < 4; ++r) {
        float s = 0.f;
#pragma unroll
        for (int j = 0; j < 4; ++j) s += acc[i][j][r] * acc[i][j][r];
        s += __shfl_xor(s, 1, 64);
        s += __shfl_xor(s, 2, 64);
        s += __shfl_xor(s, 4, 64);
        s += __shfl_xor(s, 8, 64);
        if (rl == 0)
          atomicAdd(&rqs[b * 192 + mb + i * 16 + q4 * 4 + r], s);
      }
  }
}

// ---------------- depthwise 3x3, pad 1 (optional fused sumsq) ----------------
template <bool FUSE_NORM>
__global__ __launch_bounds__(256) void dwconv_kernel(
    const u16* __restrict__ kv, const float* __restrict__ dww,
    u16* __restrict__ dst, int cbase, int dstCstride, float* __restrict__ rks) {
  __shared__ __align__(16) u16 sp[HW];
  const int c = blockIdx.x;       // 0..191
  const int b = blockIdx.y;       // 0..7
  const int c2 = cbase + c;       // channel in kv (0..383)
  const u16* src = kv + ((long)b * 384 + c2) * HW;
  u16* out = dst + ((long)b * dstCstride + c) * HW;
  const int tid = threadIdx.x;
#pragma unroll
  for (int it = 0; it < 8; ++it)
    ((u16x8*)sp)[it * 256 + tid] = ((const u16x8*)src)[it * 256 + tid];
  __syncthreads();
  float w9[9];
#pragma unroll
  for (int t = 0; t < 9; ++t) w9[t] = dww[c2 * 9 + t];
  float ssum = 0.f;
  for (int o = 0; o < 8; ++o) {
    const int base = o * 2048 + tid * 8;
    const int yy = base >> 7;
    const int x0 = base & 127;
    float vv[3][10];
#pragma unroll
    for (int r = 0; r < 3; ++r) {
      int yr = yy + r - 1;
      if (yr >= 0 && yr < 128) {
        const u16* rp = sp + yr * 128 + x0;
        u16x8 mid = *(const u16x8*)rp;
#pragma unroll
        for (int i2 = 0; i2 < 8; ++i2) vv[r][1 + i2] = bf2f(mid[i2]);
        vv[r][0] = (x0 > 0)   ? bf2f(rp[-1]) : 0.f;
        vv[r][9] = (x0 < 120) ? bf2f(rp[8])  : 0.f;
      } else {
#pragma unroll
        for (int i2 = 0; i2 < 10; ++i2) vv[r][i2] = 0.f;
      }
    }
    u16x8 ov;
#pragma unroll
    for (int i2 = 0; i2 < 8; ++i2) {
      float s = 0.f;
#pragma unroll
      for (int r = 0; r < 3; ++r)
#pragma unroll
        for (int d = 0; d < 3; ++d) s += w9[r * 3 + d] * vv[r][i2 + d];
      if constexpr (FUSE_NORM) ssum += s * s;
      ov[i2] = f2bf(s);
    }
    *(u16x8*)(out + base) = ov;
  }
  if constexpr (FUSE_NORM) {
#pragma unroll
    for (int off = 32; off; off >>= 1) ssum += __shfl_down(ssum, off, 64);
    if ((tid & 63) == 0) atomicAdd(&rks[b * 192 + c], ssum);
  }
}

// ---------------- Gram, split-K: 32 (b,h) x 8 k-chunks, atomicAdd ----------------
__global__ __launch_bounds__(256) void gram_kernel(
    const u16* __restrict__ qq, const u16* __restrict__ kk, float* __restrict__ gram) {
  __shared__ float red[4 * 2304];
  const int bh = blockIdx.x;             // 0..31
  const int kc = blockIdx.y;             // 0..7
  const int b = bh >> 2, h = bh & 3;
  const u16* qb = qq + ((long)b * 192 + h * 48) * HW;
  const u16* kb = kk + ((long)b * 192 + h * 48) * HW;
  const int tid = threadIdx.x, w = tid >> 6, lane = tid & 63;
  const int rl = lane & 15, q4 = lane >> 4;
  f32x4 acc[3][3];
#pragma unroll
  for (int i = 0; i < 3; ++i)
#pragma unroll
    for (int j = 0; j < 3; ++j) acc[i][j] = f32x4{0.f, 0.f, 0.f, 0.f};
  for (int tt = 0; tt < 16; ++tt) {
    const int k0 = ((kc * 16 + tt) * 4 + w) * 32 + q4 * 8;
    bf16x8 af[3], bfr[3];
#pragma unroll
    for (int i = 0; i < 3; ++i) af[i] = *(const bf16x8*)(qb + (long)(i * 16 + rl) * HW + k0);
#pragma unroll
    for (int j = 0; j < 3; ++j) bfr[j] = *(const bf16x8*)(kb + (long)(j * 16 + rl) * HW + k0);
#pragma unroll
    for (int i = 0; i < 3; ++i)
#pragma unroll
      for (int j = 0; j < 3; ++j)
        acc[i][j] = __builtin_amdgcn_mfma_f32_16x16x32_bf16(af[i], bfr[j], acc[i][j], 0, 0, 0);
  }
#pragma unroll
  for (int i = 0; i < 3; ++i)
#pragma unroll
    for (int j = 0; j < 3; ++j)
#pragma unroll
      for (int r = 0; r < 4; ++r)
        red[w * 2304 + (i * 16 + q4 * 4 + r) * 48 + j * 16 + rl] = acc[i][j][r];
  __syncthreads();
  for (int e = tid; e < 2304; e += 256)
    atomicAdd(&gram[(long)bh * 2304 + e], red[e] + red[2304 + e] + red[4608 + e] + red[6912 + e]);
}

// ---------------- softmax over dl (one wave per (b,h,cl) row) ----------------
__global__ __launch_bounds__(64) void softmax_kernel(
    const float* __restrict__ gram, const float* __restrict__ rqs,
    const float* __restrict__ rks, const float* __restrict__ temperature,
    float* __restrict__ attn) {
  const int R = blockIdx.x;            // b*192 + h*48 + cl
  const int lane = threadIdx.x;
  const int b = R / 192;
  const int h = (R % 192) / 48;
  const float ts = temperature[h] * 3.8712010109078907f;  // ln(48)
  const float rq = rsqrtf(fmaxf(rqs[R], 1e-24f));
  float val = -3.0e38f;
  if (lane < 48) {
    const float rk = rsqrtf(fmaxf(rks[b * 192 + h * 48 + lane], 1e-24f));
    val = gram[(long)R * 48 + lane] * rq * rk * ts;
  }
  float mx = val;
#pragma unroll
  for (int off = 32; off; off >>= 1) mx = fmaxf(mx, __shfl_xor(mx, off, 64));
  float ex = (lane < 48) ? expf(val - mx) : 0.f;
  float sm = ex;
#pragma unroll
  for (int off = 32; off; off >>= 1) sm += __shfl_xor(sm, off, 64);
  if (lane < 48) attn[(long)R * 48 + lane] = ex / sm;
}

// ---------------- PA[b][o][dg] = sum_cl proj[o][hg*48+cl] * attn[b,hg,cl,dl] ----
__global__ __launch_bounds__(192) void pa_kernel(
    const float* __restrict__ proj_w, const float* __restrict__ attn,
    u16* __restrict__ PA) {
  const int b = blockIdx.x;     // 0..7
  const int o = blockIdx.y;     // 0..191
  const int dg = threadIdx.x;   // 0..191
  const int hg = dg / 48, dl = dg % 48;
  const float* arow = attn + ((long)(b * 4 + hg) * 48) * 48 + dl;
  const float* prow = proj_w + o * 192 + hg * 48;
  float s = 0.f;
#pragma unroll
  for (int cl = 0; cl < 48; ++cl) s += prow[cl] * arow[(long)cl * 48];
  PA[((long)b * 192 + o) * 192 + dg] = f2bf(s);
}

// ---------------- launch ----------------
extern "C" void kernel_launch(void* const* d_in, const int* in_sizes, int n_in,
                              void* d_out, int out_size, void* d_ws, size_t ws_size,
                              hipStream_t stream) {
  (void)in_sizes; (void)n_in; (void)out_size; (void)ws_size;
  const float* x        = (const float*)d_in[0];
  const float* y        = (const float*)d_in[1];
  const float* kv_w     = (const float*)d_in[2];
  const float* kv_dw_w  = (const float*)d_in[3];
  const float* q_w      = (const float*)d_in[4];
  const float* q_dw_w   = (const float*)d_in[5];
  const float* proj_w   = (const float*)d_in[6];
  const float* temperature = (const float*)d_in[7];

  char* ws = (char*)d_ws;
  u16* KV = (u16*)(ws + 0L);           // kv[8][384][HW]; later v into ch 0..191
  u16* R0 = (u16*)(ws + 100663296L);   // k [8][192][HW]
  u16* R1 = (u16*)(ws + 150994944L);   // q [8][192][HW]
  u16* R2 = (u16*)(ws + 201326592L);   // yT -> xT -> vT [8][HW][192]
  char* tail = ws + 251658240L;
  u16*   zp   = (u16*)(tail + 0);        // 512 B zeros
  float* rqs  = (float*)(tail + 512);    // 6144 B
  float* rks  = (float*)(tail + 6656);   // 6144 B
  float* gram = (float*)(tail + 12800);  // 294912 B
  float* attn = (float*)(tail + 307712); // 294912 B
  u16*   W1   = (u16*)(tail + 602624);   // 147456 B
  u16*   W4   = (u16*)(tail + 750080);   // 663552 B
  u16*   PA   = (u16*)(tail + 1413632);  // 589824 B

  hipMemsetAsync(tail, 0, 307712, stream);   // zp + rqs + rks + gram
  pack_w1<<<288, 256, 0, stream>>>(kv_w, W1);
  make_w4<<<1728, 192, 0, stream>>>(q_w, q_dw_w, W4);

  // ---- q path: yT -> q (3x3 merged) with fused rq ----
  transpose_kernel<float><<<dim3(512, 6, 8), 256, 0, stream>>>(y, R2, 192);
  gemm_kernel<9, true, true><<<dim3(64, 1, 8), 512, 0, stream>>>(W4, R2, R1, zp, 192, 0, rqs);

  // ---- kv path ----
  transpose_kernel<float><<<dim3(512, 6, 8), 256, 0, stream>>>(x, R2, 192);
  gemm_kernel<1, true, false><<<dim3(64, 2, 8), 512, 0, stream>>>(W1, R2, KV, zp, 384, 0, nullptr);
  dwconv_kernel<true><<<dim3(192, 8), 256, 0, stream>>>(KV, kv_dw_w, R0, 0, 192, rks);
  dwconv_kernel<false><<<dim3(192, 8), 256, 0, stream>>>(KV, kv_dw_w, KV, 192, 384, nullptr);
  transpose_kernel<u16><<<dim3(512, 6, 8), 256, 0, stream>>>(KV, R2, 384);

  // ---- attention + projection ----
  gram_kernel<<<dim3(32, 8), 256, 0, stream>>>(R1, R0, gram);
  softmax_kernel<<<1536, 64, 0, stream>>>(gram, rqs, rks, temperature, attn);
  pa_kernel<<<dim3(8, 192), 192, 0, stream>>>(proj_w, attn, PA);
  gemm_kernel<1, false, false><<<dim3(64, 1, 8), 512, 0, stream>>>(PA, R2, d_out, zp, 192, 36864, nullptr);
}

// Round 5
// 591.085 us; speedup vs baseline: 1.1526x; 1.0880x over previous
//
#include <hip/hip_runtime.h>

// MDTA attention, B=8 C=192 H=W=128 heads=4 (ch=48), all-bf16 MFMA pipeline.
// R5: gemm ported to m201-style phase schedule: BK=32, 4-deep LDS buffer
//     rotation (112KB), prefetch distance 3, 2 phases per K-tile
//     {ds_read | stage-part -> barrier -> lgkmcnt(0) -> setprio+12 MFMA -> barrier},
//     counted per-wave vmcnt once per K-tile (never 0 in steady state).

#define HW 16384

using f32x4  = __attribute__((ext_vector_type(4))) float;
using bf16x8 = __attribute__((ext_vector_type(8))) __bf16;
using u16x8  = __attribute__((ext_vector_type(8))) unsigned short;
typedef unsigned short u16;

__device__ __forceinline__ u16 f2bf(float f) {
  unsigned u = __builtin_bit_cast(unsigned, f);
  u = (u + 0x7fffu + ((u >> 16) & 1u)) >> 16;   // RNE
  return (u16)u;
}
__device__ __forceinline__ float bf2f(u16 s) {
  unsigned u = ((unsigned)s) << 16;
  return __builtin_bit_cast(float, u);
}

// async global->LDS, 16B/lane; LDS dest is wave-uniform base + lane*16
__device__ __forceinline__ void g2l16(const void* g, void* l) {
  __builtin_amdgcn_global_load_lds(
      (const __attribute__((address_space(1))) unsigned int*)g,
      (__attribute__((address_space(3))) unsigned int*)l, 16, 0, 0);
}

// ---------------- W1 pack: kv_w [384][192] fp32 -> bf16 ----------------
__global__ __launch_bounds__(256) void pack_w1(
    const float* __restrict__ kv_w, u16* __restrict__ W1) {
  int i = blockIdx.x * 256 + threadIdx.x;
  W1[i] = f2bf(kv_w[i]);
}

// ---------------- W4[o][seg*192+c] = sum_ic q_dw_w[(o*192+ic)*9+seg]*q_w[ic*192+c]
__global__ __launch_bounds__(192) void make_w4(
    const float* __restrict__ q_w, const float* __restrict__ q_dw_w,
    u16* __restrict__ W4) {
  const int o = blockIdx.x / 9, seg = blockIdx.x % 9;
  const int c = threadIdx.x;
  float s = 0.f;
  for (int ic = 0; ic < 192; ++ic)
    s += q_dw_w[(o * 192 + ic) * 9 + seg] * q_w[ic * 192 + c];
  W4[o * 1728 + seg * 192 + c] = f2bf(s);
}

// ---------------- transpose [b][C][HW] -> [b][HW][192] bf16 ----------------
template <typename TIn>
__global__ __launch_bounds__(256) void transpose_kernel(
    const TIn* __restrict__ src, u16* __restrict__ dst, int srcCstride) {
  __shared__ u16 tile[32][34];
  const int bz = blockIdx.z;
  const int n0 = blockIdx.x * 32;
  const int c0 = blockIdx.y * 32;
  const TIn* s = src + (long)bz * srcCstride * HW;
  u16* d = dst + (long)bz * HW * 192;
  const int tx = threadIdx.x & 31;
  const int ty = threadIdx.x >> 5;
#pragma unroll
  for (int i = 0; i < 32; i += 8) {
    if constexpr (sizeof(TIn) == 4)
      tile[ty + i][tx] = f2bf(((const float*)s)[(long)(c0 + ty + i) * HW + n0 + tx]);
    else
      tile[ty + i][tx] = ((const u16*)s)[(long)(c0 + ty + i) * HW + n0 + tx];
  }
  __syncthreads();
#pragma unroll
  for (int i = 0; i < 32; i += 8)
    d[(long)(n0 + ty + i) * 192 + c0 + tx] = tile[tx][ty + i];
}

// ---------------- main MFMA GEMM, BK=32, 4-buffer rotation, 2 phases/K-tile ----
// C[b][m][n] = sum_k A[m][k] * Bt[b][n][k], K = NSEG*192.
// NSEG==9: segment s=(dy,dx) reads Bt row (n + dy*128 + dx), zero page at borders.
// Tile 192x256x32; 8 waves 2x4, each 96x64 out. LDS slot = staging lane identity:
// frag read addr = slot_base + lane*16B (conflict-free).
// Buffer beta = kt&3; per K-tile per wave: A loads (1 or 2) + B loads (2).
// Waves 0-3: kL=4 loads/tile, waves 4-7: kL=3. vmcnt(2kL) once per K-tile.
template <int NSEG, bool OUT_BF16, bool FUSE_RQ>
__global__ __launch_bounds__(512, 2) void gemm_kernel(
    const u16* __restrict__ A, const u16* __restrict__ Bt,
    void* __restrict__ Cout, const u16* __restrict__ zp,
    int M, long aBatchStride, float* __restrict__ rqs) {
  __shared__ __align__(16) u16 sh[57344];   // 4 bufs x (A 12 + B 16 slots) x 512 u16
  constexpr int NT = NSEG * 6;              // BK=32 steps
  const int Ktot = NSEG * 192;
  const int tid = threadIdx.x;
  const int w = tid >> 6;                   // 0..7
  const int lane = tid & 63;
  const int rl = lane & 15;
  const int q4 = lane >> 4;
  const int wm = w >> 2, wn = w & 3;        // 2x4 wave grid
  const int b = blockIdx.z;
  const int n0 = blockIdx.x * 256;
  const int m0 = blockIdx.y * 192;

  const u16* Ab = A + (long)b * aBatchStride + (long)m0 * Ktot;
  const u16* Btb = Bt + (long)b * HW * 192;
  const char* zpp = (const char*)zp + q4 * 16;
  const bool hasA2 = (w < 4);

  // A staging sources: slot w (rows w*16+rl), waves 0-3 also slot 8+w (rows 128+w*16+rl)
  const char* asrcA  = (const char*)(Ab + (long)(w * 16 + rl) * Ktot) + q4 * 16;
  const char* asrcA2 = (const char*)(Ab + (long)(128 + w * 16 + rl) * Ktot) + q4 * 16;

  // B staging sources: n-subtiles 2w, 2w+1
  const char* bsrc0[2];
  int bx[2], by[2];
#pragma unroll
  for (int jj = 0; jj < 2; ++jj) {
    int n = n0 + (2 * w + jj) * 16 + rl;
    bsrc0[jj] = (const char*)(Btb + (long)n * 192) + q4 * 16;
    bx[jj] = n & 127;
    by[jj] = n >> 7;
  }

  f32x4 acc[6][4];
#pragma unroll
  for (int i = 0; i < 6; ++i)
#pragma unroll
    for (int j = 0; j < 4; ++j) acc[i][j] = f32x4{0.f, 0.f, 0.f, 0.f};

  const int lo = lane * 8;   // u16 offset of this lane's frag slot

  // stage A part of K-tile kt (1-2 gload_lds)
  auto stageA = [&](int kt) {
    u16* base = sh + (kt & 3) * 14336;
    const long ak = (long)kt * 64;
    g2l16(asrcA + ak, base + w * 512);
    if (hasA2) g2l16(asrcA2 + ak, base + (8 + w) * 512);
  };
  // stage B part of K-tile kt (2 gload_lds)
  auto stageB = [&](int kt) {
    u16* base = sh + (kt & 3) * 14336 + 6144;
    if constexpr (NSEG == 1) {
      const long bk = (long)kt * 64;
      g2l16(bsrc0[0] + bk, base + (2 * w) * 512);
      g2l16(bsrc0[1] + bk, base + (2 * w + 1) * 512);
    } else {
      const int seg = kt / 6;
      const long bk = (long)(kt - seg * 6) * 64;
      const int dy = seg / 3 - 1, dx = seg % 3 - 1;
      const long roff = (long)(dy * 128 + dx) * 384;
#pragma unroll
      for (int jj = 0; jj < 2; ++jj) {
        bool ok = ((unsigned)(bx[jj] + dx) < 128u) && ((unsigned)(by[jj] + dy) < 128u);
        const char* bp = ok ? bsrc0[jj] + roff : zpp;
        g2l16(bp + bk, base + (2 * w + jj) * 512);
      }
    }
  };

  // prologue: 3 K-tiles in flight
  stageA(0); stageB(0);
  stageA(1); stageB(1);
  stageA(2); stageB(2);
  if (hasA2) asm volatile("s_waitcnt vmcnt(8)" ::: "memory");   // L(0) landed
  else       asm volatile("s_waitcnt vmcnt(6)" ::: "memory");
  __builtin_amdgcn_s_barrier();

  for (int kt = 0; kt < NT; ++kt) {
    const u16* base = sh + (kt & 3) * 14336;
    const u16* baseB = base + 6144;
    // ---- phase 1: m-rows 0..2 ----
    bf16x8 af0[3], bfv[4];
#pragma unroll
    for (int i = 0; i < 3; ++i)
      af0[i] = *(const bf16x8*)&base[(wm * 6 + i) * 512 + lo];
#pragma unroll
    for (int j = 0; j < 4; ++j)
      bfv[j] = *(const bf16x8*)&baseB[(wn * 4 + j) * 512 + lo];
    if (kt + 3 < NT) stageA(kt + 3);
    __builtin_amdgcn_s_barrier();
    asm volatile("s_waitcnt lgkmcnt(0)" ::: "memory");
    __builtin_amdgcn_sched_barrier(0);
    __builtin_amdgcn_s_setprio(1);
#pragma unroll
    for (int i = 0; i < 3; ++i)
#pragma unroll
      for (int j = 0; j < 4; ++j)
        acc[i][j] = __builtin_amdgcn_mfma_f32_16x16x32_bf16(af0[i], bfv[j], acc[i][j], 0, 0, 0);
    __builtin_amdgcn_s_setprio(0);
    __builtin_amdgcn_s_barrier();
    // ---- phase 2: m-rows 3..5 ----
    bf16x8 af1[3];
#pragma unroll
    for (int i = 0; i < 3; ++i)
      af1[i] = *(const bf16x8*)&base[(wm * 6 + 3 + i) * 512 + lo];
    if (kt + 3 < NT) stageB(kt + 3);
    // counted wait: ensure L(kt+1) landed before next K-tile's reads
    if (kt <= NT - 4) {
      if (hasA2) asm volatile("s_waitcnt vmcnt(8)" ::: "memory");
      else       asm volatile("s_waitcnt vmcnt(6)" ::: "memory");
    } else if (kt == NT - 3) {
      if (hasA2) asm volatile("s_waitcnt vmcnt(4)" ::: "memory");
      else       asm volatile("s_waitcnt vmcnt(3)" ::: "memory");
    } else if (kt == NT - 2) {
      asm volatile("s_waitcnt vmcnt(0)" ::: "memory");
    }
    __builtin_amdgcn_s_barrier();
    asm volatile("s_waitcnt lgkmcnt(0)" ::: "memory");
    __builtin_amdgcn_sched_barrier(0);
    __builtin_amdgcn_s_setprio(1);
#pragma unroll
    for (int i = 0; i < 3; ++i)
#pragma unroll
      for (int j = 0; j < 4; ++j)
        acc[3 + i][j] = __builtin_amdgcn_mfma_f32_16x16x32_bf16(af1[i], bfv[j], acc[3 + i][j], 0, 0, 0);
    __builtin_amdgcn_s_setprio(0);
    __builtin_amdgcn_s_barrier();
  }

  // epilogue: D row m = quad*4+reg, col n = lane&15  [m89/m91 mapping]
  const int mb = m0 + wm * 96;
  const int nb = n0 + wn * 64;
  if constexpr (OUT_BF16) {
    u16* Cb = (u16*)Cout + (long)b * M * HW;
#pragma unroll
    for (int i = 0; i < 6; ++i)
#pragma unroll
      for (int j = 0; j < 4; ++j)
#pragma unroll
        for (int r = 0; r < 4; ++r)
          Cb[(long)(mb + i * 16 + q4 * 4 + r) * HW + nb + j * 16 + rl] = f2bf(acc[i][j][r]);
  } else {
    float* Cb = (float*)Cout + (long)b * M * HW;
#pragma unroll
    for (int i = 0; i < 6; ++i)
#pragma unroll
      for (int j = 0; j < 4; ++j)
#pragma unroll
        for (int r = 0; r < 4; ++r)
          Cb[(long)(mb + i * 16 + q4 * 4 + r) * HW + nb + j * 16 + rl] = acc[i][j][r];
  }
  if constexpr (FUSE_RQ) {
    // per-row sum of squares over this block's 256-col slice -> atomicAdd
#pragma unroll
    for (int i = 0; i < 6; ++i)
#pragma unroll
      for (int r = 0; r < 4; ++r) {
        float s = 0.f;
#pragma unroll
        for (int j = 0; j < 4; ++j) s += acc[i][j][r] * acc[i][j][r];
        s += __shfl_xor(s, 1, 64);
        s += __shfl_xor(s, 2, 64);
        s += __shfl_xor(s, 4, 64);
        s += __shfl_xor(s, 8, 64);
        if (rl == 0)
          atomicAdd(&rqs[b * 192 + mb + i * 16 + q4 * 4 + r], s);
      }
  }
}

// ---------------- depthwise 3x3, pad 1 (optional fused sumsq) ----------------
template <bool FUSE_NORM>
__global__ __launch_bounds__(256) void dwconv_kernel(
    const u16* __restrict__ kv, const float* __restrict__ dww,
    u16* __restrict__ dst, int cbase, int dstCstride, float* __restrict__ rks) {
  __shared__ __align__(16) u16 sp[HW];
  const int c = blockIdx.x;       // 0..191
  const int b = blockIdx.y;       // 0..7
  const int c2 = cbase + c;       // channel in kv (0..383)
  const u16* src = kv + ((long)b * 384 + c2) * HW;
  u16* out = dst + ((long)b * dstCstride + c) * HW;
  const int tid = threadIdx.x;
#pragma unroll
  for (int it = 0; it < 8; ++it)
    ((u16x8*)sp)[it * 256 + tid] = ((const u16x8*)src)[it * 256 + tid];
  __syncthreads();
  float w9[9];
#pragma unroll
  for (int t = 0; t < 9; ++t) w9[t] = dww[c2 * 9 + t];
  float ssum = 0.f;
  for (int o = 0; o < 8; ++o) {
    const int base = o * 2048 + tid * 8;
    const int yy = base >> 7;
    const int x0 = base & 127;
    float vv[3][10];
#pragma unroll
    for (int r = 0; r < 3; ++r) {
      int yr = yy + r - 1;
      if (yr >= 0 && yr < 128) {
        const u16* rp = sp + yr * 128 + x0;
        u16x8 mid = *(const u16x8*)rp;
#pragma unroll
        for (int i2 = 0; i2 < 8; ++i2) vv[r][1 + i2] = bf2f(mid[i2]);
        vv[r][0] = (x0 > 0)   ? bf2f(rp[-1]) : 0.f;
        vv[r][9] = (x0 < 120) ? bf2f(rp[8])  : 0.f;
      } else {
#pragma unroll
        for (int i2 = 0; i2 < 10; ++i2) vv[r][i2] = 0.f;
      }
    }
    u16x8 ov;
#pragma unroll
    for (int i2 = 0; i2 < 8; ++i2) {
      float s = 0.f;
#pragma unroll
      for (int r = 0; r < 3; ++r)
#pragma unroll
        for (int d = 0; d < 3; ++d) s += w9[r * 3 + d] * vv[r][i2 + d];
      if constexpr (FUSE_NORM) ssum += s * s;
      ov[i2] = f2bf(s);
    }
    *(u16x8*)(out + base) = ov;
  }
  if constexpr (FUSE_NORM) {
#pragma unroll
    for (int off = 32; off; off >>= 1) ssum += __shfl_down(ssum, off, 64);
    if ((tid & 63) == 0) atomicAdd(&rks[b * 192 + c], ssum);
  }
}

// ---------------- Gram, split-K: 32 (b,h) x 8 k-chunks, atomicAdd ----------------
__global__ __launch_bounds__(256) void gram_kernel(
    const u16* __restrict__ qq, const u16* __restrict__ kk, float* __restrict__ gram) {
  __shared__ float red[4 * 2304];
  const int bh = blockIdx.x;             // 0..31
  const int kc = blockIdx.y;             // 0..7
  const int b = bh >> 2, h = bh & 3;
  const u16* qb = qq + ((long)b * 192 + h * 48) * HW;
  const u16* kb = kk + ((long)b * 192 + h * 48) * HW;
  const int tid = threadIdx.x, w = tid >> 6, lane = tid & 63;
  const int rl = lane & 15, q4 = lane >> 4;
  f32x4 acc[3][3];
#pragma unroll
  for (int i = 0; i < 3; ++i)
#pragma unroll
    for (int j = 0; j < 3; ++j) acc[i][j] = f32x4{0.f, 0.f, 0.f, 0.f};
  for (int tt = 0; tt < 16; ++tt) {
    const int k0 = ((kc * 16 + tt) * 4 + w) * 32 + q4 * 8;
    bf16x8 af[3], bfr[3];
#pragma unroll
    for (int i = 0; i < 3; ++i) af[i] = *(const bf16x8*)(qb + (long)(i * 16 + rl) * HW + k0);
#pragma unroll
    for (int j = 0; j < 3; ++j) bfr[j] = *(const bf16x8*)(kb + (long)(j * 16 + rl) * HW + k0);
#pragma unroll
    for (int i = 0; i < 3; ++i)
#pragma unroll
      for (int j = 0; j < 3; ++j)
        acc[i][j] = __builtin_amdgcn_mfma_f32_16x16x32_bf16(af[i], bfr[j], acc[i][j], 0, 0, 0);
  }
#pragma unroll
  for (int i = 0; i < 3; ++i)
#pragma unroll
    for (int j = 0; j < 3; ++j)
#pragma unroll
      for (int r = 0; r < 4; ++r)
        red[w * 2304 + (i * 16 + q4 * 4 + r) * 48 + j * 16 + rl] = acc[i][j][r];
  __syncthreads();
  for (int e = tid; e < 2304; e += 256)
    atomicAdd(&gram[(long)bh * 2304 + e], red[e] + red[2304 + e] + red[4608 + e] + red[6912 + e]);
}

// ---------------- softmax over dl (one wave per (b,h,cl) row) ----------------
__global__ __launch_bounds__(64) void softmax_kernel(
    const float* __restrict__ gram, const float* __restrict__ rqs,
    const float* __restrict__ rks, const float* __restrict__ temperature,
    float* __restrict__ attn) {
  const int R = blockIdx.x;            // b*192 + h*48 + cl
  const int lane = threadIdx.x;
  const int b = R / 192;
  const int h = (R % 192) / 48;
  const float ts = temperature[h] * 3.8712010109078907f;  // ln(48)
  const float rq = rsqrtf(fmaxf(rqs[R], 1e-24f));
  float val = -3.0e38f;
  if (lane < 48) {
    const float rk = rsqrtf(fmaxf(rks[b * 192 + h * 48 + lane], 1e-24f));
    val = gram[(long)R * 48 + lane] * rq * rk * ts;
  }
  float mx = val;
#pragma unroll
  for (int off = 32; off; off >>= 1) mx = fmaxf(mx, __shfl_xor(mx, off, 64));
  float ex = (lane < 48) ? expf(val - mx) : 0.f;
  float sm = ex;
#pragma unroll
  for (int off = 32; off; off >>= 1) sm += __shfl_xor(sm, off, 64);
  if (lane < 48) attn[(long)R * 48 + lane] = ex / sm;
}

// ---------------- PA[b][o][dg] = sum_cl proj[o][hg*48+cl] * attn[b,hg,cl,dl] ----
__global__ __launch_bounds__(192) void pa_kernel(
    const float* __restrict__ proj_w, const float* __restrict__ attn,
    u16* __restrict__ PA) {
  const int b = blockIdx.x;     // 0..7
  const int o = blockIdx.y;     // 0..191
  const int dg = threadIdx.x;   // 0..191
  const int hg = dg / 48, dl = dg % 48;
  const float* arow = attn + ((long)(b * 4 + hg) * 48) * 48 + dl;
  const float* prow = proj_w + o * 192 + hg * 48;
  float s = 0.f;
#pragma unroll
  for (int cl = 0; cl < 48; ++cl) s += prow[cl] * arow[(long)cl * 48];
  PA[((long)b * 192 + o) * 192 + dg] = f2bf(s);
}

// ---------------- launch ----------------
extern "C" void kernel_launch(void* const* d_in, const int* in_sizes, int n_in,
                              void* d_out, int out_size, void* d_ws, size_t ws_size,
                              hipStream_t stream) {
  (void)in_sizes; (void)n_in; (void)out_size; (void)ws_size;
  const float* x        = (const float*)d_in[0];
  const float* y        = (const float*)d_in[1];
  const float* kv_w     = (const float*)d_in[2];
  const float* kv_dw_w  = (const float*)d_in[3];
  const float* q_w      = (const float*)d_in[4];
  const float* q_dw_w   = (const float*)d_in[5];
  const float* proj_w   = (const float*)d_in[6];
  const float* temperature = (const float*)d_in[7];

  char* ws = (char*)d_ws;
  u16* KV = (u16*)(ws + 0L);           // kv[8][384][HW]; later v into ch 0..191
  u16* R0 = (u16*)(ws + 100663296L);   // k [8][192][HW]
  u16* R1 = (u16*)(ws + 150994944L);   // q [8][192][HW]
  u16* R2 = (u16*)(ws + 201326592L);   // yT -> xT -> vT [8][HW][192]
  char* tail = ws + 251658240L;
  u16*   zp   = (u16*)(tail + 0);        // 512 B zeros
  float* rqs  = (float*)(tail + 512);    // 6144 B
  float* rks  = (float*)(tail + 6656);   // 6144 B
  float* gram = (float*)(tail + 12800);  // 294912 B
  float* attn = (float*)(tail + 307712); // 294912 B
  u16*   W1   = (u16*)(tail + 602624);   // 147456 B
  u16*   W4   = (u16*)(tail + 750080);   // 663552 B
  u16*   PA   = (u16*)(tail + 1413632);  // 589824 B

  hipMemsetAsync(tail, 0, 307712, stream);   // zp + rqs + rks + gram
  pack_w1<<<288, 256, 0, stream>>>(kv_w, W1);
  make_w4<<<1728, 192, 0, stream>>>(q_w, q_dw_w, W4);

  // ---- q path: yT -> q (3x3 merged) with fused rq ----
  transpose_kernel<float><<<dim3(512, 6, 8), 256, 0, stream>>>(y, R2, 192);
  gemm_kernel<9, true, true><<<dim3(64, 1, 8), 512, 0, stream>>>(W4, R2, R1, zp, 192, 0, rqs);

  // ---- kv path ----
  transpose_kernel<float><<<dim3(512, 6, 8), 256, 0, stream>>>(x, R2, 192);
  gemm_kernel<1, true, false><<<dim3(64, 2, 8), 512, 0, stream>>>(W1, R2, KV, zp, 384, 0, nullptr);
  dwconv_kernel<true><<<dim3(192, 8), 256, 0, stream>>>(KV, kv_dw_w, R0, 0, 192, rks);
  dwconv_kernel<false><<<dim3(192, 8), 256, 0, stream>>>(KV, kv_dw_w, KV, 192, 384, nullptr);
  transpose_kernel<u16><<<dim3(512, 6, 8), 256, 0, stream>>>(KV, R2, 384);

  // ---- attention + projection ----
  gram_kernel<<<dim3(32, 8), 256, 0, stream>>>(R1, R0, gram);
  softmax_kernel<<<1536, 64, 0, stream>>>(gram, rqs, rks, temperature, attn);
  pa_kernel<<<dim3(8, 192), 192, 0, stream>>>(proj_w, attn, PA);
  gemm_kernel<1, false, false><<<dim3(64, 1, 8), 512, 0, stream>>>(PA, R2, d_out, zp, 192, 36864, nullptr);
}